// Round 2
// baseline (366.728 us; speedup 1.0000x reference)
//
#include <hip/hip_runtime.h>

#define NB 16
#define LL 32
#define NORD 24
#define NSTEPS 64
#define MMLEN 3073

// 1/j! for j=0..25 (f32)
__device__ __constant__ float INVF[26] = {
    1.0f, 1.0f, 5.0e-1f, 1.66666672e-1f, 4.16666679e-2f, 8.33333377e-3f,
    1.38888892e-3f, 1.98412701e-4f, 2.48015876e-5f, 2.75573195e-6f,
    2.75573188e-7f, 2.50521089e-8f, 2.08767563e-9f, 1.60590438e-10f,
    1.14707458e-11f, 7.64716373e-13f, 4.77947733e-14f, 2.81145725e-15f,
    1.56192069e-16f, 8.22063525e-18f, 4.11031762e-19f, 1.95729410e-20f,
    8.89679139e-22f, 3.86817017e-23f, 1.61173757e-24f, 6.44695028e-26f};

// trapezoidal pulse, f32 arithmetic replicating the jnp reference
__device__ __forceinline__ float pulsef(float ts) {
    const float rise = 5.0e-10f;
    const float w    = 9.999999999999999e-10f;
    const float e1   = 1.4999999999999998e-9f;
    const float e2   = 1.9999999999999997e-9f;
    const float fall = 5.0e-10f;
    if (ts < rise) return ts / rise;
    if (ts < e1)   return 1.0f;
    if (ts < e2)   return 1.0f - ((ts - w) - rise) / fall;
    return 0.0f;
}

// One term of the power recursion: t <- (A*dt) * t, midv <- new mid component.
// Chain layout per lane: 16 consecutive chain positions of one branch.
__device__ __forceinline__ void term_step(float (&t)[16], float& midv,
                                          const float (&al)[16],
                                          const float (&be)[16],
                                          float cMb, bool head) {
    // mid_new = sum_b cM[b] * t_old[head_b]  (valid in head lanes after xor-reduce)
    float hv = head ? (cMb * t[0]) : 0.0f;
    hv += __shfl_xor(hv, 4);
    hv += __shfl_xor(hv, 8);
    hv += __shfl_xor(hv, 16);
    hv += __shfl_xor(hv, 32);
    // chain-boundary neighbors
    float lv = __shfl_up(t[15], 1);    // pos-1 from previous lane (same branch, q>0)
    float rv = __shfl_down(t[0], 1);   // pos+16 boundary (q<3); q==3 has be[15]==0
    float left0 = head ? midv : lv;    // head rows couple to v_mid

    float nt[16];
    nt[0] = al[0] * left0 + be[0] * t[1];
#pragma unroll
    for (int i = 1; i < 15; ++i)
        nt[i] = al[i] * t[i - 1] + be[i] * t[i + 1];
    nt[15] = al[15] * t[14] + be[15] * rv;

    midv = hv;
#pragma unroll
    for (int i = 0; i < 16; ++i) t[i] = nt[i];
}

__global__ __launch_bounds__(64) void sspuf_wave(
    const int*   __restrict__ swp,
    const float* __restrict__ mismatch,
    const float* __restrict__ gm_c,
    const float* __restrict__ gm_l,
    const float* __restrict__ c_val,
    const float* __restrict__ l_val,
    const float* __restrict__ tp,
    float*       __restrict__ out)
{
    const int star = blockIdx.x;
    const int l = threadIdx.x;         // 0..63
    const int b = l >> 2;              // branch
    const int q = l & 3;               // quarter of the 64-state chain
    const bool head = (q == 0);
    const float dt = tp[0] / 64.0f;

    const float* mm = mismatch + star * MMLEN;
    const float* mb = mm + b * 192;

    // ---- per-lane tridiagonal coefficients of (A*dt) for chain pos p=16q+i ----
    // pos 2k = i[b,k]:  d/dt = gml0_k/Lm_k * pos(2k-1)  - gml1_k/Lm_k * pos(2k+1)
    //                   (k==0: left neighbor is v_mid, coeff *= sw_b)
    // pos 2k+1 = v[b,k]: d/dt = gmc0_k/C_k * pos(2k)    - gmc1_k/C_k * pos(2k+2)
    //                   (k==31: no right neighbor)
    float al[16], be[16];
    const int P0 = q << 4;
#pragma unroll
    for (int i = 0; i < 16; ++i) {
        int p = P0 + i;
        int k = p >> 1;
        if ((p & 1) == 0) {
            float gml0 = mb[64 + 2 * k]     * gm_l[2 * k];
            float gml1 = mb[64 + 2 * k + 1] * gm_l[2 * k + 1];
            float Lm   = 1e-9f * (mb[160 + k] * l_val[k]);
            float a    = dt * (gml0 / Lm);
            if (k == 0) a *= (float)swp[b];
            al[i] = a;
            be[i] = -dt * (gml1 / Lm);
        } else {
            float gmc0 = mb[2 * k]     * gm_c[2 * k];
            float gmc1 = mb[2 * k + 1] * gm_c[2 * k + 1];
            float C    = 1e-9f * (mb[128 + k] * c_val[k]);
            al[i] = dt * (gmc0 / C);
            be[i] = (k < 31) ? (-dt * (gmc1 / C)) : 0.0f;
        }
    }
    const float c_mid = 1e-9f * (mm[MMLEN - 1] * c_val[LL]);
    const float cMb   = -dt * ((float)swp[b] / c_mid);   // mid-row coeff (head lanes)

    // ================= phib = Phi @ Bv via the series =================
    // t_0 = Bv (mid = 1/c_mid); phib = dt * sum_{j>=0} t_j / (j+1)!
    float t[16];
#pragma unroll
    for (int i = 0; i < 16; ++i) t[i] = 0.0f;
    float midv = 1.0f / c_mid;         // only head lanes consume it; harmless elsewhere
    float phib[16];
#pragma unroll
    for (int i = 0; i < 16; ++i) phib[i] = 0.0f;
    float phibm = INVF[1] * (1.0f / c_mid);
#pragma unroll
    for (int j = 1; j <= NORD; ++j) {
        term_step(t, midv, al, be, cMb, head);
        const float f = INVF[j + 1];
#pragma unroll
        for (int i = 0; i < 16; ++i) phib[i] = fmaf(f, t[i], phib[i]);
        phibm = fmaf(f, midv, phibm);
    }
#pragma unroll
    for (int i = 0; i < 16; ++i) phib[i] *= dt;
    phibm *= dt;

    // ================= 64 ZOH steps: x <- E x + phib*u =================
    float x[16];
#pragma unroll
    for (int i = 0; i < 16; ++i) x[i] = 0.0f;
    float xm = 0.0f;

    for (int s = 0; s < NSTEPS; ++s) {
        const float u = pulsef(((float)s + 0.5f) * dt);
        float acc[16];
#pragma unroll
        for (int i = 0; i < 16; ++i) { acc[i] = x[i]; t[i] = x[i]; }
        midv = xm;
        float accm = xm;
#pragma unroll
        for (int j = 1; j <= NORD; ++j) {
            term_step(t, midv, al, be, cMb, head);
            const float f = INVF[j];
#pragma unroll
            for (int i = 0; i < 16; ++i) acc[i] = fmaf(f, t[i], acc[i]);
            accm = fmaf(f, midv, accm);
        }
#pragma unroll
        for (int i = 0; i < 16; ++i) x[i] = fmaf(phib[i], u, acc[i]);
        xm = fmaf(phibm, u, accm);
    }

    // output = xm(star 0) - xm(star 1); out zeroed via memset
    if (l == 0) atomicAdd(out, (star == 0) ? xm : -xm);
}

extern "C" void kernel_launch(void* const* d_in, const int* in_sizes, int n_in,
                              void* d_out, int out_size, void* d_ws, size_t ws_size,
                              hipStream_t stream) {
    const int*   swp      = (const int*)d_in[0];
    const float* mismatch = (const float*)d_in[1];
    const float* gm_c     = (const float*)d_in[2];
    const float* gm_l     = (const float*)d_in[3];
    const float* c_val    = (const float*)d_in[4];
    const float* l_val    = (const float*)d_in[5];
    const float* tp       = (const float*)d_in[6];
    float* out = (float*)d_out;

    hipMemsetAsync(out, 0, sizeof(float), stream);
    sspuf_wave<<<dim3(2), dim3(64), 0, stream>>>(
        swp, mismatch, gm_c, gm_l, c_val, l_val, tp, out);
}

// Round 3
// 224.980 us; speedup vs baseline: 1.6300x; 1.6300x over previous
//
#include <hip/hip_runtime.h>

#define NB 16
#define LL 32
#define NORD 24
#define NSTEPS 64
#define MMLEN 3073

// trapezoidal pulse, f32 arithmetic replicating the jnp reference
__device__ __forceinline__ float pulsef(float ts) {
    const float rise = 5.0e-10f;
    const float w    = 9.999999999999999e-10f;
    const float e1   = 1.4999999999999998e-9f;
    const float e2   = 1.9999999999999997e-9f;
    const float fall = 5.0e-10f;
    if (ts < rise) return ts / rise;
    if (ts < e1)   return 1.0f;
    if (ts < e2)   return 1.0f - ((ts - w) - rise) / fall;
    return 0.0f;
}

// VALU-pipe cross-lane move within a 16-lane DPP row
template <int CTRL>
__device__ __forceinline__ float dpp_movf(float x) {
    return __int_as_float(__builtin_amdgcn_update_dpp(
        0, __float_as_int(x), CTRL, 0xF, 0xF, true));
}

// One term of the power recursion: t <- (A*dt) * t, midv <- new mid component.
// Layout: lane l -> branch b=l&15, quarter q=l>>4; t[i] = chain pos 16q+i.
// Branch heads (pos 0) live in DPP row 0 (lanes 0..15).
__device__ __forceinline__ void term_step(float (&t)[16], float& midv,
                                          const float (&al)[16],
                                          const float (&be)[16],
                                          float cMb, bool head) {
    // mid_new = sum_b cM[b]*t_old[head_b] : DPP row all-reduce (VALU pipe).
    // Rows 1..3 compute garbage sums that are never consumed.
    float hv = cMb * t[0];
    hv += dpp_movf<0xB1>(hv);    // quad_perm xor1
    hv += dpp_movf<0x4E>(hv);    // quad_perm xor2
    hv += dpp_movf<0x124>(hv);   // row_ror:4
    hv += dpp_movf<0x128>(hv);   // row_ror:8
    // chain-boundary halo (only 2 LDS-pipe ops per term, independent)
    float lv = __shfl_up(t[15], 16);   // pos 16q-1 from lane l-16 (q>0)
    float rv = __shfl_down(t[0], 16);  // pos 16q+16 from lane l+16 (q<3; q==3 be[15]==0)
    float left0 = head ? midv : lv;    // head rows couple to v_mid (previous midv)

    float nt[16];
    nt[0] = al[0] * left0 + be[0] * t[1];
#pragma unroll
    for (int i = 1; i < 15; ++i)
        nt[i] = al[i] * t[i - 1] + be[i] * t[i + 1];
    nt[15] = al[15] * t[14] + be[15] * rv;

    midv = hv;
#pragma unroll
    for (int i = 0; i < 16; ++i) t[i] = nt[i];
}

__global__ __launch_bounds__(64) void sspuf_wave(
    const int*   __restrict__ swp,
    const float* __restrict__ mismatch,
    const float* __restrict__ gm_c,
    const float* __restrict__ gm_l,
    const float* __restrict__ c_val,
    const float* __restrict__ l_val,
    const float* __restrict__ tp,
    float*       __restrict__ out)
{
    // 1/j! for j=0..25, folded to literals by the unrolled loops
    constexpr float INVF[26] = {
        1.0f, 1.0f, 5.0e-1f, 1.66666672e-1f, 4.16666679e-2f, 8.33333377e-3f,
        1.38888892e-3f, 1.98412701e-4f, 2.48015876e-5f, 2.75573195e-6f,
        2.75573188e-7f, 2.50521089e-8f, 2.08767563e-9f, 1.60590438e-10f,
        1.14707458e-11f, 7.64716373e-13f, 4.77947733e-14f, 2.81145725e-15f,
        1.56192069e-16f, 8.22063525e-18f, 4.11031762e-19f, 1.95729410e-20f,
        8.89679139e-22f, 3.86817017e-23f, 1.61173757e-24f, 6.44695028e-26f};

    const int star = blockIdx.x;
    const int l = threadIdx.x;         // 0..63
    const int b = l & 15;              // branch
    const int q = l >> 4;              // quarter of the 64-state chain
    const bool head = (q == 0);
    const float dt = tp[0] / 64.0f;

    const float* mm = mismatch + star * MMLEN;
    const float* mb = mm + b * 192;

    // ---- per-lane tridiagonal coefficients of (A*dt) for chain pos p=16q+i ----
    // pos 2k   = i[b,k]: d/dt = gml0_k/Lm_k * pos(2k-1) - gml1_k/Lm_k * pos(2k+1)
    //            (k==0: left neighbor is v_mid, coeff *= sw_b)
    // pos 2k+1 = v[b,k]: d/dt = gmc0_k/C_k * pos(2k) - gmc1_k/C_k * pos(2k+2)
    //            (k==31: no right neighbor)
    float al[16], be[16];
    const int P0 = q << 4;
#pragma unroll
    for (int i = 0; i < 16; ++i) {
        int p = P0 + i;
        int k = p >> 1;
        if ((p & 1) == 0) {
            float gml0 = mb[64 + 2 * k]     * gm_l[2 * k];
            float gml1 = mb[64 + 2 * k + 1] * gm_l[2 * k + 1];
            float Lm   = 1e-9f * (mb[160 + k] * l_val[k]);
            float a    = dt * (gml0 / Lm);
            if (k == 0) a *= (float)swp[b];
            al[i] = a;
            be[i] = -dt * (gml1 / Lm);
        } else {
            float gmc0 = mb[2 * k]     * gm_c[2 * k];
            float gmc1 = mb[2 * k + 1] * gm_c[2 * k + 1];
            float C    = 1e-9f * (mb[128 + k] * c_val[k]);
            al[i] = dt * (gmc0 / C);
            be[i] = (k < 31) ? (-dt * (gmc1 / C)) : 0.0f;
        }
    }
    const float c_mid = 1e-9f * (mm[MMLEN - 1] * c_val[LL]);
    const float cMb   = -dt * ((float)swp[b] / c_mid);   // mid-row coeff per branch

    // ================= phib = Phi @ Bv via the series =================
    // t_0 = Bv (mid = 1/c_mid); phib = dt * sum_{j>=0} t_j / (j+1)!
    float t[16];
#pragma unroll
    for (int i = 0; i < 16; ++i) t[i] = 0.0f;
    float midv = 1.0f / c_mid;
    float phib[16];
#pragma unroll
    for (int i = 0; i < 16; ++i) phib[i] = 0.0f;
    float phibm = INVF[1] * (1.0f / c_mid);
#pragma unroll
    for (int j = 1; j <= NORD; ++j) {
        term_step(t, midv, al, be, cMb, head);
        const float f = INVF[j + 1];
#pragma unroll
        for (int i = 0; i < 16; ++i) phib[i] = fmaf(f, t[i], phib[i]);
        phibm = fmaf(f, midv, phibm);
    }
#pragma unroll
    for (int i = 0; i < 16; ++i) phib[i] *= dt;
    phibm *= dt;

    // ================= 64 ZOH steps: x <- E x + phib*u =================
    float x[16];
#pragma unroll
    for (int i = 0; i < 16; ++i) x[i] = 0.0f;
    float xm = 0.0f;

    for (int s = 0; s < NSTEPS; ++s) {
        const float u = pulsef(((float)s + 0.5f) * dt);
        float acc[16];
#pragma unroll
        for (int i = 0; i < 16; ++i) { acc[i] = x[i]; t[i] = x[i]; }
        midv = xm;
        float accm = xm;
#pragma unroll
        for (int j = 1; j <= NORD; ++j) {
            term_step(t, midv, al, be, cMb, head);
            const float f = INVF[j];
#pragma unroll
            for (int i = 0; i < 16; ++i) acc[i] = fmaf(f, t[i], acc[i]);
            accm = fmaf(f, midv, accm);
        }
#pragma unroll
        for (int i = 0; i < 16; ++i) x[i] = fmaf(phib[i], u, acc[i]);
        xm = fmaf(phibm, u, accm);
    }

    // output = xm(star 0) - xm(star 1); out zeroed via memset
    if (l == 0) atomicAdd(out, (star == 0) ? xm : -xm);
}

extern "C" void kernel_launch(void* const* d_in, const int* in_sizes, int n_in,
                              void* d_out, int out_size, void* d_ws, size_t ws_size,
                              hipStream_t stream) {
    const int*   swp      = (const int*)d_in[0];
    const float* mismatch = (const float*)d_in[1];
    const float* gm_c     = (const float*)d_in[2];
    const float* gm_l     = (const float*)d_in[3];
    const float* c_val    = (const float*)d_in[4];
    const float* l_val    = (const float*)d_in[5];
    const float* tp       = (const float*)d_in[6];
    float* out = (float*)d_out;

    hipMemsetAsync(out, 0, sizeof(float), stream);
    sspuf_wave<<<dim3(2), dim3(64), 0, stream>>>(
        swp, mismatch, gm_c, gm_l, c_val, l_val, tp, out);
}

// Round 4
// 163.512 us; speedup vs baseline: 2.2428x; 1.3759x over previous
//
#include <hip/hip_runtime.h>

#define NORD 24
#define LL 32
#define MMLEN 3073

// 1/j! for j=0..25
static constexpr float INVF[26] = {
    1.0f, 1.0f, 5.0e-1f, 1.66666672e-1f, 4.16666679e-2f, 8.33333377e-3f,
    1.38888892e-3f, 1.98412701e-4f, 2.48015876e-5f, 2.75573195e-6f,
    2.75573188e-7f, 2.50521089e-8f, 2.08767563e-9f, 1.60590438e-10f,
    1.14707458e-11f, 7.64716373e-13f, 4.77947733e-14f, 2.81145725e-15f,
    1.56192069e-16f, 8.22063525e-18f, 4.11031762e-19f, 1.95729410e-20f,
    8.89679139e-22f, 3.86817017e-23f, 1.61173757e-24f, 6.44695028e-26f};

// trapezoidal pulse, f32 arithmetic replicating the jnp reference
__device__ __forceinline__ float pulsef(float ts) {
    const float rise = 5.0e-10f;
    const float w    = 9.999999999999999e-10f;
    const float e1   = 1.4999999999999998e-9f;
    const float e2   = 1.9999999999999997e-9f;
    const float fall = 5.0e-10f;
    if (ts < rise) return ts / rise;
    if (ts < e1)   return 1.0f;
    if (ts < e2)   return 1.0f - ((ts - w) - rise) / fall;
    return 0.0f;
}

// VALU-pipe cross-lane move within a 16-lane DPP row
template <int CTRL>
__device__ __forceinline__ float dpp_movf(float x) {
    return __int_as_float(__builtin_amdgcn_update_dpp(
        0, __float_as_int(x), CTRL, 0xF, 0xF, true));
}

// One term of the power recursion: t <- (M*dt) * t, midv <- new mid component.
// Layout: lane l -> branch b=l&15, quarter q=l>>4; t[i] = chain pos 16q+i.
// Branch heads (pos 0) live in DPP row 0 (lanes 0..15). Works for A and A^T
// (structure identical; only the coefficient arrays differ).
__device__ __forceinline__ void term_step(float (&t)[16], float& midv,
                                          const float (&al)[16],
                                          const float (&be)[16],
                                          float cMb, bool head) {
    // mid_new = sum_b cM[b]*t_old[head_b] : DPP row all-reduce (VALU pipe)
    float hv = cMb * t[0];
    hv += dpp_movf<0xB1>(hv);    // quad_perm xor1
    hv += dpp_movf<0x4E>(hv);    // quad_perm xor2
    hv += dpp_movf<0x124>(hv);   // row_ror:4
    hv += dpp_movf<0x128>(hv);   // row_ror:8
    // chain-boundary halo
    float lv = __shfl_up(t[15], 16);   // pos 16q-1 from lane l-16 (q>0)
    float rv = __shfl_down(t[0], 16);  // pos 16q+16 from lane l+16 (q<3; q==3 be[15]==0)
    float left0 = head ? midv : lv;    // head rows couple to v_mid

    float nt[16];
    nt[0] = al[0] * left0 + be[0] * t[1];
#pragma unroll
    for (int i = 1; i < 15; ++i)
        nt[i] = al[i] * t[i - 1] + be[i] * t[i + 1];
    nt[15] = al[15] * t[14] + be[15] * rv;

    midv = hv;
#pragma unroll
    for (int i = 0; i < 16; ++i) t[i] = nt[i];
}

// x <- (sum_{j<=NORD} (M dt)^j / j!) x ; xm is the mid component
__device__ __forceinline__ void eapply(float (&x)[16], float& xm,
                                       const float (&al)[16],
                                       const float (&be)[16],
                                       float cMb, bool head) {
    float t[16], acc[16];
#pragma unroll
    for (int i = 0; i < 16; ++i) { t[i] = x[i]; acc[i] = x[i]; }
    float midv = xm, accm = xm;
#pragma unroll
    for (int j = 1; j <= NORD; ++j) {
        term_step(t, midv, al, be, cMb, head);
        const float f = INVF[j];
#pragma unroll
        for (int i = 0; i < 16; ++i) acc[i] = fmaf(f, t[i], acc[i]);
        accm = fmaf(f, midv, accm);
    }
#pragma unroll
    for (int i = 0; i < 16; ++i) x[i] = acc[i];
    xm = accm;
}

// Meet-in-the-middle: per star, wave 0 runs the forward chain
// (phib series, then z31 = E^31 phib), wave 1 runs the backward chain
// (w_a = (E^T)^a e_mid, a=0..32) folding u-weighted accumulators.
// xm(T) = P0 . z0 + P31 . z31, with
//   P0  = sum_{a=0}^{30} u_{63-a} w_a   (k = a      in 0..30)
//   P31 = sum_{a=0}^{32} u_{32-a} w_a   (k = 31 + a in 31..63)
__global__ __launch_bounds__(128) void sspuf_mitm(
    const int*   __restrict__ swp,
    const float* __restrict__ mismatch,
    const float* __restrict__ gm_c,
    const float* __restrict__ gm_l,
    const float* __restrict__ c_val,
    const float* __restrict__ l_val,
    const float* __restrict__ tp,
    float*       __restrict__ out)
{
    const int star = blockIdx.x;
    const int tid  = threadIdx.x;
    const int wave = tid >> 6;
    const int l    = tid & 63;
    const int b    = l & 15;           // branch
    const int q    = l >> 4;           // quarter of the 64-state chain
    const bool head = (q == 0);
    const float dt = tp[0] / 64.0f;

    const float* mm = mismatch + star * MMLEN;
    const float* mb = mm + b * 192;
    const float swb   = (float)swp[b];
    const float c_mid = 1e-9f * (mm[MMLEN - 1] * c_val[LL]);

    __shared__ float zbuf[2][1032];    // [0]=z0 (phib), [1]=z31

    // backward-wave accumulators (live across the post-barrier epilogue)
    float Pa[16], Pb[16];
    float Pam = 0.0f, Pbm = 0.0f;
#pragma unroll
    for (int i = 0; i < 16; ++i) { Pa[i] = 0.0f; Pb[i] = 0.0f; }

    const int P0i = q << 4;

    if (wave == 0) {
        // ---------------- forward chain ----------------
        // coefficients of (A*dt): pos 2k = i[b,k], pos 2k+1 = v[b,k]
        float al[16], be[16];
#pragma unroll
        for (int i = 0; i < 16; ++i) {
            int p = P0i + i, k = p >> 1;
            if ((p & 1) == 0) {
                float Lm = 1e-9f * (mb[160 + k] * l_val[k]);
                float a  = dt * ((mb[64 + 2 * k] * gm_l[2 * k]) / Lm);
                if (k == 0) a *= swb;
                al[i] = a;
                be[i] = -dt * ((mb[64 + 2 * k + 1] * gm_l[2 * k + 1]) / Lm);
            } else {
                float C = 1e-9f * (mb[128 + k] * c_val[k]);
                al[i] = dt * ((mb[2 * k] * gm_c[2 * k]) / C);
                be[i] = (k < 31) ? (-dt * ((mb[2 * k + 1] * gm_c[2 * k + 1]) / C))
                                 : 0.0f;
            }
        }
        const float cMb = -dt * (swb / c_mid);

        // phib = dt * sum_{j>=0} t_j / (j+1)!,  t_0 = Bv (mid = 1/c_mid)
        float t[16], z[16];
#pragma unroll
        for (int i = 0; i < 16; ++i) { t[i] = 0.0f; z[i] = 0.0f; }
        float midv = 1.0f / c_mid;
        float zm = INVF[1] * midv;
#pragma unroll
        for (int j = 1; j <= NORD; ++j) {
            term_step(t, midv, al, be, cMb, head);
            const float f = INVF[j + 1];
#pragma unroll
            for (int i = 0; i < 16; ++i) z[i] = fmaf(f, t[i], z[i]);
            zm = fmaf(f, midv, zm);
        }
#pragma unroll
        for (int i = 0; i < 16; ++i) z[i] *= dt;
        zm *= dt;

#pragma unroll
        for (int i = 0; i < 16; ++i) zbuf[0][l * 16 + i] = z[i];
        if (l == 0) zbuf[0][1024] = zm;

        for (int s = 0; s < 31; ++s) eapply(z, zm, al, be, cMb, head);

#pragma unroll
        for (int i = 0; i < 16; ++i) zbuf[1][l * 16 + i] = z[i];
        if (l == 0) zbuf[1][1024] = zm;
    } else {
        // ---------------- backward chain (A^T) ----------------
        // alT[p] = dt*A[p-1][p] (p=0: mid coupling = cM_b)
        // beT[p] = dt*A[p+1][p] (p=63: 0); midT row coeff = dt*A[head_b][mid]
        float al[16], be[16];
#pragma unroll
        for (int i = 0; i < 16; ++i) {
            int p = P0i + i, k = p >> 1;
            if ((p & 1) == 0) {
                if (p == 0) {
                    al[i] = -dt * (swb / c_mid);
                } else {
                    float Cm1 = 1e-9f * (mb[128 + (k - 1)] * c_val[k - 1]);
                    al[i] = -dt * ((mb[2 * (k - 1) + 1] * gm_c[2 * (k - 1) + 1]) / Cm1);
                }
                float C = 1e-9f * (mb[128 + k] * c_val[k]);
                be[i] = dt * ((mb[2 * k] * gm_c[2 * k]) / C);
            } else {
                float Lm = 1e-9f * (mb[160 + k] * l_val[k]);
                al[i] = -dt * ((mb[64 + 2 * k + 1] * gm_l[2 * k + 1]) / Lm);
                if (k < 31) {
                    float Lp1 = 1e-9f * (mb[160 + (k + 1)] * l_val[k + 1]);
                    be[i] = dt * ((mb[64 + 2 * (k + 1)] * gm_l[2 * (k + 1)]) / Lp1);
                } else {
                    be[i] = 0.0f;
                }
            }
        }
        float Lm0 = 1e-9f * (mb[160] * l_val[0]);
        const float cMbT = dt * ((swb * (mb[64] * gm_l[0])) / Lm0);

        // w_0 = e_mid
        float w[16];
#pragma unroll
        for (int i = 0; i < 16; ++i) w[i] = 0.0f;
        float wm = 1.0f;

        for (int a = 0; a <= 32; ++a) {
            const float ua = (a <= 30) ? pulsef(((float)(63 - a) + 0.5f) * dt) : 0.0f;
            const float ub = pulsef(((float)(32 - a) + 0.5f) * dt);
#pragma unroll
            for (int i = 0; i < 16; ++i) {
                Pa[i] = fmaf(ua, w[i], Pa[i]);
                Pb[i] = fmaf(ub, w[i], Pb[i]);
            }
            Pam = fmaf(ua, wm, Pam);
            Pbm = fmaf(ub, wm, Pbm);
            if (a < 32) eapply(w, wm, al, be, cMbT, head);
        }
    }

    __syncthreads();

    if (wave == 1) {
        float part = 0.0f;
#pragma unroll
        for (int i = 0; i < 16; ++i)
            part += Pa[i] * zbuf[0][l * 16 + i] + Pb[i] * zbuf[1][l * 16 + i];
        if (l == 0)
            part += Pam * zbuf[0][1024] + Pbm * zbuf[1][1024];
        // 64-lane sum: DPP row reduce + cross-row shuffles
        part += dpp_movf<0xB1>(part);
        part += dpp_movf<0x4E>(part);
        part += dpp_movf<0x124>(part);
        part += dpp_movf<0x128>(part);
        part += __shfl_xor(part, 16);
        part += __shfl_xor(part, 32);
        if (l == 0) atomicAdd(out, (star == 0) ? part : -part);
    }
}

extern "C" void kernel_launch(void* const* d_in, const int* in_sizes, int n_in,
                              void* d_out, int out_size, void* d_ws, size_t ws_size,
                              hipStream_t stream) {
    const int*   swp      = (const int*)d_in[0];
    const float* mismatch = (const float*)d_in[1];
    const float* gm_c     = (const float*)d_in[2];
    const float* gm_l     = (const float*)d_in[3];
    const float* c_val    = (const float*)d_in[4];
    const float* l_val    = (const float*)d_in[5];
    const float* tp       = (const float*)d_in[6];
    float* out = (float*)d_out;

    hipMemsetAsync(out, 0, sizeof(float), stream);
    sspuf_mitm<<<dim3(2), dim3(128), 0, stream>>>(
        swp, mismatch, gm_c, gm_l, c_val, l_val, tp, out);
}